// Round 2
// baseline (464.266 us; speedup 1.0000x reference)
//
#include <hip/hip_runtime.h>
#include <math.h>

#define NNODES 100000
#define NEDGES 1600000
#define NPOS   4096      // 32 seqs * 128 steps
#define NSEQ   32
#define TSTEPS 128
#define NB     256       // LSTM blocks: 32 seq-groups x 8 members

typedef float f32x4 __attribute__((ext_vector_type(4)));

// ---- ws layout (bytes) ----
#define OFF_SLOT   0          // int[100000]  (dead after k_pregemm; overlaid below)
#define OFF_AGG    400128     // float[4096*128]
#define OFF_CNT    2497280    // float[4096]
#define OFF_WF     2513664    // float[1024*128]
#define OFF_BIASF  3037952    // float[1024]
#define OFF_PREG   3042048    // float[128][32s][8m][4q][32d]
#define OFF_HS     19819264   // float[129][32][256]
// overlay on slotmap region (used only after k_pregemm):
// X (fast, XCD-L2) buffer: u64 pairs[32s][2][256] at byte 0      (131072 B)
// Y (slow, agent/IF$) buffer: same shape at byte 131072           (131072 B)
// CTRL at byte 262144: int[16] {xcd_ctr[8], arrivals, ovf, pad...}
#define OFF_GHB    0
#define YOFFP      16384      // Y offset in 8-byte pairs
#define OFF_CTRL   262144

// ---------------- init ----------------
__global__ void k_init(int* slotmap, float* agg, float* cnt, float* hs0) {
  int i = blockIdx.x * blockDim.x + threadIdx.x;
  int stride = gridDim.x * blockDim.x;
  for (int idx = i; idx < 4096 * 128; idx += stride) agg[idx] = 0.f;
  for (int idx = i; idx < NNODES; idx += stride) slotmap[idx] = -1;
  for (int idx = i; idx < 4096; idx += stride) cnt[idx] = 0.f;
  for (int idx = i; idx < 8192; idx += stride) hs0[idx] = 0.f;
}

// zero X+Y pair regions + control block (after k_pregemm, before k_lstm).
// Replay-critical. val=0.0f, tag=0  ==> h(0)=0 published for step 0 on both paths.
__global__ void k_init2(unsigned long long* ghb, int* ctrl) {
  int i = blockIdx.x * blockDim.x + threadIdx.x;
  int stride = gridDim.x * blockDim.x;
  for (int k = i; k < NSEQ * 2 * 256 * 2; k += stride) ghb[k] = 0ULL;
  if (i < 16) ctrl[i] = 0;
}

// ---------------- mark needed nodes ----------------
__global__ void k_mark(const int* __restrict__ input_ids, int* __restrict__ slotmap) {
  int p = blockIdx.x * blockDim.x + threadIdx.x;
  if (p < NPOS) atomicCAS(&slotmap[input_ids[p]], -1, p);
}

// ---------------- edge pass: masked segment-sum ----------------
__global__ void k_edge(const int* __restrict__ src, const int* __restrict__ dst,
                       const float* __restrict__ ev, const float* __restrict__ emb,
                       const int* __restrict__ slotmap,
                       float* __restrict__ agg, float* __restrict__ cnt) {
  int e = blockIdx.x * 256 + threadIdx.x;
  int lane = threadIdx.x & 63;
  int d = dst[e];
  int slot = slotmap[d];
  int sn = 0; float vv = 0.f;
  if (slot >= 0) { sn = src[e]; vv = ev[e]; }
  unsigned long long m = __ballot(slot >= 0);
  while (m) {
    int j = __ffsll(m) - 1;
    m &= m - 1;
    int sl = __shfl(slot, j);
    int s2 = __shfl(sn, j);
    float v = __shfl(vv, j);
    float2 em = *(const float2*)&emb[(size_t)s2 * 128 + 2 * lane];
    atomicAdd(&agg[sl * 128 + 2 * lane],     em.x * v);
    atomicAdd(&agg[sl * 128 + 2 * lane + 1], em.y * v);
    if (lane == 0) atomicAdd(&cnt[sl], 1.f);
  }
}

// ---------------- divide by count ----------------
__global__ void k_div(float* __restrict__ agg, const float* __restrict__ cnt) {
  int i = blockIdx.x * blockDim.x + threadIdx.x;
  agg[i] /= fmaxf(cnt[i >> 7], 1.f);
}

// ---------------- fuse W_f = w_ih @ W1, bias_f ----------------
__global__ void k_fuse(const float* __restrict__ w_ih, const float* __restrict__ W1,
                       const float* __restrict__ b1, const float* __restrict__ b_ih,
                       const float* __restrict__ b_hh,
                       float* __restrict__ Wf, float* __restrict__ bf) {
  int row = blockIdx.x;
  int e = threadIdx.x;
  float acc = 0.f;
  for (int m2 = 0; m2 < 256; ++m2) acc += w_ih[row * 256 + m2] * W1[m2 * 128 + e];
  Wf[row * 128 + e] = acc;
  if (e == 0) {
    float bacc = b_ih[row] + b_hh[row];
    for (int m2 = 0; m2 < 256; ++m2) bacc += w_ih[row * 256 + m2] * b1[m2];
    bf[row] = bacc;
  }
}

// ---------------- pre-gates GEMM: preg[t][s][m][q][d] ----------------
__global__ __launch_bounds__(256, 2) void k_pregemm(
    const float* __restrict__ hnode, const float* __restrict__ Wf,
    const float* __restrict__ bf, const int* __restrict__ slotmap,
    const int* __restrict__ input_ids, float* __restrict__ preg) {
  __shared__ float Ash[64][132];
  __shared__ float Bsh[64][132];
  __shared__ int slots[64];
  int tid = threadIdx.x;
  int bm = (blockIdx.x & 63) * 64;
  int bn = (blockIdx.x >> 6) * 64;
  if (tid < 64) slots[tid] = slotmap[input_ids[bm + tid]];
  __syncthreads();
#pragma unroll
  for (int i = 0; i < 8; ++i) {
    int idx = tid + 256 * i;
    int r = idx >> 5, c = idx & 31;
    *(float4*)&Ash[r][c * 4] = *(const float4*)&hnode[slots[r] * 128 + c * 4];
    *(float4*)&Bsh[r][c * 4] = *(const float4*)&Wf[(bn + r) * 128 + c * 4];
  }
  __syncthreads();
  int tx = tid & 15, ty = tid >> 4;
  float acc[4][4] = {};
  for (int k = 0; k < 128; k += 4) {
    float4 a[4], bb[4];
#pragma unroll
    for (int i = 0; i < 4; ++i) a[i] = *(const float4*)&Ash[tx + 16 * i][k];
#pragma unroll
    for (int j = 0; j < 4; ++j) bb[j] = *(const float4*)&Bsh[ty + 16 * j][k];
#pragma unroll
    for (int i = 0; i < 4; ++i)
#pragma unroll
      for (int j = 0; j < 4; ++j)
        acc[i][j] += a[i].x * bb[j].x + a[i].y * bb[j].y + a[i].z * bb[j].z + a[i].w * bb[j].w;
  }
#pragma unroll
  for (int j = 0; j < 4; ++j) {
    int row = bn + ty + 16 * j;
    float bias = bf[row];
    int q  = row >> 8;
    int mm = (row >> 5) & 7;
    int dl = row & 31;
#pragma unroll
    for (int i = 0; i < 4; ++i) {
      int p = bm + tx + 16 * i;
      int s = p >> 7, tt = p & 127;
      preg[(((size_t)(tt * 32 + s) * 8 + mm) * 4 + q) * 32 + dl] = acc[i][j] + bias;
    }
  }
}

// ---------------- LSTM: 32 seq-groups x 8 members, XCD-pinned dual-path exchange ----
// Blocks self-organize by PHYSICAL chiplet: each block reads HW_REG_XCC_ID and takes
// a rank r in its XCD (device atomic). r<32 claims role xcd*32+r, decoded so that all
// 8 members of a sequence share one XCD => the X exchange (plain sc0 store -> shared
// XCD L2 -> sc0 poll) is a true L2 round trip. Uneven packing: overflow blocks wait
// for all arrivals, then claim leftover roles deterministically; the Y (agent/IF$)
// path in the poll keeps any placement correct. Tags make any matched read valid.
__global__ __launch_bounds__(256, 1) void k_lstm(
    const float* __restrict__ w_hh, const float* __restrict__ preg,
    float* __restrict__ hs, unsigned long long* __restrict__ ghb,
    int* __restrict__ ctrl) {
  __shared__ float h_lds[512];           // 2 x 256 floats, xor-swizzled
  __shared__ int sh_role;
  int tid = threadIdx.x;

  if (tid == 0) {
    unsigned xcd;
    asm volatile("s_getreg_b32 %0, hwreg(HW_REG_XCC_ID)" : "=s"(xcd));
    xcd &= 7;
    int r = atomicAdd(&ctrl[xcd], 1);          // rank within my physical XCD
    int role;
    if (r < 32) {
      role = (int)xcd * 32 + r;
      atomicAdd(&ctrl[8], 1);                  // arrivals (ctr add already complete: r consumed)
    } else {
      int o = atomicAdd(&ctrl[9], 1);          // overflow rank
      atomicAdd(&ctrl[8], 1);
      while (__hip_atomic_load(&ctrl[8], __ATOMIC_RELAXED, __HIP_MEMORY_SCOPE_AGENT) < NB) {}
      int acc = 0; role = 0;
      for (int x2 = 0; x2 < 8; ++x2) {
        int c = __hip_atomic_load(&ctrl[x2], __ATOMIC_RELAXED, __HIP_MEMORY_SCOPE_AGENT);
        if (c > 32) c = 32;
        int miss = 32 - c;
        if (o >= acc && o < acc + miss) role = x2 * 32 + c + (o - acc);
        acc += miss;
      }
    }
    sh_role = role;
  }
  __syncthreads();
  const int role = sh_role;
  const int s = 4 * (role >> 5) + ((role >> 3) & 3);  // sequence (XCD-local group)
  const int m = role & 7;                             // member: owns dims 32m..32m+31

  int lane = tid & 63, wave = tid >> 6;
  int x = lane & 7, seg = lane >> 3;     // seg 0..7: k-range [32seg, 32seg+32)
  int combo = x + 8 * wave;              // local dim 0..31
  const int isSeg0 = (seg == 0);

  // weights: rows q*256 + 32m + combo, k-slice [32seg, 32seg+32)
  f32x4 wv[4][8];
#pragma unroll
  for (int q = 0; q < 4; ++q) {
    const float* wp = w_hh + (q * 256 + 32 * m + combo) * 256 + seg * 32;
#pragma unroll
    for (int i = 0; i < 8; ++i) wv[q][i] = *(const f32x4*)(wp + 4 * i);
  }

  unsigned long long* xbase = ghb + s * 512;   // X: [2][256] pairs
  // swizzled scalar LDS index for dim d = tid (matches f32x4 read pattern)
  int fi = tid >> 2, jj = tid & 3;
  int ldsw = (((fi >> 3) * 8) + ((fi & 7) ^ (fi >> 3))) * 4 + jj;

  float c_st = 0.f;                       // cell state (seg0 lanes)

  for (int t = 0; t < TSTEPS; ++t) {
    // poll own pair until tag == t; the value in the same 8B is h[t][tid]
    const unsigned long long* px = xbase + (t & 1) * 256 + tid;
    unsigned long long pr;
    int gd = 0;
    for (;;) {
      asm volatile("global_load_dwordx2 %0, %1, off sc0\n\ts_waitcnt vmcnt(0)"
                   : "=v"(pr) : "v"(px) : "memory");
      if ((unsigned)(pr >> 32) == (unsigned)t) break;
      if ((gd & 7) == 7) {
        pr = __hip_atomic_load(px + YOFFP, __ATOMIC_RELAXED, __HIP_MEMORY_SCOPE_AGENT);
        if ((unsigned)(pr >> 32) == (unsigned)t) break;
      }
      if (++gd >= (1 << 20)) break;
    }
    // prefetch pre-gates AFTER the poll: L2 latency hides under LDS/barrier/dots
    float pg[4] = {0.f, 0.f, 0.f, 0.f};
    if (isSeg0) {
      const float* pb = preg + (((size_t)(t * 32 + s) * 8 + m) * 4) * 32 + combo;
#pragma unroll
      for (int q = 0; q < 4; ++q) pg[q] = pb[q * 32];
    }
    h_lds[(t & 1) * 256 + ldsw] = __uint_as_float((unsigned)pr);
    __syncthreads();
    // partial dots: 4 gate-rows x 32 k per thread
    const f32x4* lds4 = (const f32x4*)(h_lds + (t & 1) * 256);
    float acc[4] = {0.f, 0.f, 0.f, 0.f};
#pragma unroll
    for (int i = 0; i < 8; ++i) {
      f32x4 hv = lds4[seg * 8 + (i ^ seg)];
#pragma unroll
      for (int q = 0; q < 4; ++q)
        acc[q] += wv[q][i].x * hv.x + wv[q][i].y * hv.y
                + wv[q][i].z * hv.z + wv[q][i].w * hv.w;
    }
    // reduce over the 8 k-segments (lane bits 3..5)
#pragma unroll
    for (int q = 0; q < 4; ++q) {
      float v = acc[q];
      v += __shfl_xor(v, 8);
      v += __shfl_xor(v, 16);
      v += __shfl_xor(v, 32);
      acc[q] = v;
    }
    // gate math + tagged publish (seg0 lanes own dim=combo)
    if (isSeg0) {
      float gi = acc[0] + pg[0];
      float gf = acc[1] + pg[1];
      float gg = acc[2] + pg[2];
      float go = acc[3] + pg[3];
      float si = 1.f / (1.f + expf(-gi));
      float sf = 1.f / (1.f + expf(-gf));
      float so = 1.f / (1.f + expf(-go));
      float cc = sf * c_st + si * tanhf(gg);
      float hh = so * tanhf(cc);
      c_st = cc;
      unsigned long long pk =
          ((unsigned long long)(unsigned)(t + 1) << 32) |
          (unsigned long long)__float_as_uint(hh);
      unsigned long long* xp = xbase + ((t + 1) & 1) * 256 + 32 * m + combo;
      // X first (fast path into the shared XCD L2), then Y (agent/IF$ fallback)
      asm volatile("global_store_dwordx2 %0, %1, off sc0"
                   :: "v"(xp), "v"(pk) : "memory");
      __hip_atomic_store(xp + YOFFP, pk, __ATOMIC_RELAXED, __HIP_MEMORY_SCOPE_AGENT);
      hs[(size_t)(t + 1) * 8192 + s * 256 + 32 * m + combo] = hh;  // history
    }
    // no trailing barrier: LDS double-buffer + next-step barrier protect h_lds
  }
}

// ---------------- final: scores, softmax, BCE, argmax ----------------
__global__ void k_final(const float* __restrict__ hs, const int* __restrict__ mask,
                        const float* __restrict__ labels, const float* __restrict__ W2,
                        const float* __restrict__ b2, float* __restrict__ out) {
  __shared__ float scores[32];
  __shared__ float errpart[8];
  int tid = threadIdx.x;
  if (tid < 32) {
    int len = 0;
    for (int t = 0; t < 128; ++t) len += mask[tid * 128 + t];
    if (len < 1) len = 1;
    const float* hl = hs + (size_t)len * 8192 + tid * 256;
    float acc = b2[0];
    for (int k = 0; k < 256; ++k) acc += hl[k] * W2[k];
    scores[tid] = acc;
  }
  __syncthreads();
  if (tid < 8) {
    float sc[4];
#pragma unroll
    for (int i = 0; i < 4; ++i) sc[i] = scores[tid * 4 + i];
    float mx = fmaxf(fmaxf(sc[0], sc[1]), fmaxf(sc[2], sc[3]));
    float ex[4], ssum = 0.f;
#pragma unroll
    for (int i = 0; i < 4; ++i) { ex[i] = expf(sc[i] - mx); ssum += ex[i]; }
    float esum = 0.f; int am = 0; float best = -1e30f;
#pragma unroll
    for (int i = 0; i < 4; ++i) {
      float p = ex[i] / ssum;
      float li = labels[tid * 4 + i];
      esum += fmaxf(p, 0.f) - p * li + log1pf(expf(-fabsf(p)));
      if (p > best) { best = p; am = i; }
    }
    errpart[tid] = esum;
    out[1 + tid] = (float)am;
  }
  __syncthreads();
  if (tid == 0) {
    float e = 0.f;
    for (int i = 0; i < 8; ++i) e += errpart[i];
    out[0] = e / 32.f;
  }
}

extern "C" void kernel_launch(void* const* d_in, const int* in_sizes, int n_in,
                              void* d_out, int out_size, void* d_ws, size_t ws_size,
                              hipStream_t stream) {
  const int*   input_ids  = (const int*)d_in[0];
  const int*   input_mask = (const int*)d_in[1];
  const float* labels     = (const float*)d_in[2];
  const int*   src        = (const int*)d_in[3];
  const int*   dst        = (const int*)d_in[4];
  const float* ev         = (const float*)d_in[5];
  const float* node_emb   = (const float*)d_in[6];
  const float* W1         = (const float*)d_in[7];
  const float* b1         = (const float*)d_in[8];
  const float* w_ih       = (const float*)d_in[9];
  const float* w_hh       = (const float*)d_in[10];
  const float* b_ih       = (const float*)d_in[11];
  const float* b_hh       = (const float*)d_in[12];
  const float* W2         = (const float*)d_in[13];
  const float* b2         = (const float*)d_in[14];
  float* out = (float*)d_out;
  char* ws = (char*)d_ws;
  int*   slotmap = (int*)(ws + OFF_SLOT);
  float* agg     = (float*)(ws + OFF_AGG);
  float* cnt     = (float*)(ws + OFF_CNT);
  float* Wf      = (float*)(ws + OFF_WF);
  float* biasf   = (float*)(ws + OFF_BIASF);
  float* preg    = (float*)(ws + OFF_PREG);
  float* hs      = (float*)(ws + OFF_HS);
  unsigned long long* ghb = (unsigned long long*)(ws + OFF_GHB);
  int*   ctrl    = (int*)(ws + OFF_CTRL);

  hipLaunchKernelGGL(k_init,    dim3(2048), dim3(256), 0, stream, slotmap, agg, cnt, hs);
  hipLaunchKernelGGL(k_mark,    dim3(16),   dim3(256), 0, stream, input_ids, slotmap);
  hipLaunchKernelGGL(k_edge,    dim3(6250), dim3(256), 0, stream, src, dst, ev, node_emb, slotmap, agg, cnt);
  hipLaunchKernelGGL(k_div,     dim3(2048), dim3(256), 0, stream, agg, cnt);
  hipLaunchKernelGGL(k_fuse,    dim3(1024), dim3(128), 0, stream, w_ih, W1, b1, b_ih, b_hh, Wf, biasf);
  hipLaunchKernelGGL(k_pregemm, dim3(1024), dim3(256), 0, stream, agg, Wf, biasf, slotmap, input_ids, preg);
  hipLaunchKernelGGL(k_init2,   dim3(64),   dim3(256), 0, stream, ghb, ctrl);
  hipLaunchKernelGGL(k_lstm,    dim3(NB),   dim3(256), 0, stream, w_hh, preg, hs, ghb, ctrl);
  hipLaunchKernelGGL(k_final,   dim3(1),    dim3(64),  0, stream, hs, input_mask, labels, W2, b2, out);
}

// Round 3
// 377.084 us; speedup vs baseline: 1.2312x; 1.2312x over previous
//
#include <hip/hip_runtime.h>
#include <math.h>

#define NNODES 100000
#define NEDGES 1600000
#define NPOS   4096      // 32 seqs * 128 steps
#define NSEQ   32
#define TSTEPS 128
#define NB     256       // LSTM blocks: 32 seq-groups x 8 members

typedef float f32x4 __attribute__((ext_vector_type(4)));

// ---- ws layout (bytes) ----
#define OFF_SLOT   0          // int[100000]  (dead after k_pregemm; overlaid below)
#define OFF_AGG    400128     // float[4096*128]
#define OFF_CNT    2497280    // float[4096]
#define OFF_WF     2513664    // float[1024*128]
#define OFF_BIASF  3037952    // float[1024]
#define OFF_PREG   3042048    // float[128][32s][8m][4q][32d]
#define OFF_HS     19819264   // float[129][32][256]
// overlay on slotmap region (used only after k_pregemm):
// X (fast, XCD-L2) buffer: u64 pairs[32s][2][256] at byte 0      (131072 B)
// Y (slow, agent/IF$) buffer: same shape at byte 131072           (131072 B)
// CTRL at byte 262144: int[16] {xcd_ctr[8], arrivals, ovf, pad...}
#define OFF_GHB    0
#define YOFFP      16384      // Y offset in 8-byte pairs
#define OFF_CTRL   262144

// ---------------- init ----------------
__global__ void k_init(int* slotmap, float* agg, float* cnt, float* hs0) {
  int i = blockIdx.x * blockDim.x + threadIdx.x;
  int stride = gridDim.x * blockDim.x;
  for (int idx = i; idx < 4096 * 128; idx += stride) agg[idx] = 0.f;
  for (int idx = i; idx < NNODES; idx += stride) slotmap[idx] = -1;
  for (int idx = i; idx < 4096; idx += stride) cnt[idx] = 0.f;
  for (int idx = i; idx < 8192; idx += stride) hs0[idx] = 0.f;
}

// zero X+Y pair regions + control block (after k_pregemm, before k_lstm).
// Replay-critical. val=0.0f, tag=0  ==> h(0)=0 published for step 0 on both paths.
__global__ void k_init2(unsigned long long* ghb, int* ctrl) {
  int i = blockIdx.x * blockDim.x + threadIdx.x;
  int stride = gridDim.x * blockDim.x;
  for (int k = i; k < NSEQ * 2 * 256 * 2; k += stride) ghb[k] = 0ULL;
  if (i < 16) ctrl[i] = 0;
}

// ---------------- mark needed nodes ----------------
__global__ void k_mark(const int* __restrict__ input_ids, int* __restrict__ slotmap) {
  int p = blockIdx.x * blockDim.x + threadIdx.x;
  if (p < NPOS) atomicCAS(&slotmap[input_ids[p]], -1, p);
}

// ---------------- edge pass: masked segment-sum ----------------
__global__ void k_edge(const int* __restrict__ src, const int* __restrict__ dst,
                       const float* __restrict__ ev, const float* __restrict__ emb,
                       const int* __restrict__ slotmap,
                       float* __restrict__ agg, float* __restrict__ cnt) {
  int e = blockIdx.x * 256 + threadIdx.x;
  int lane = threadIdx.x & 63;
  int d = dst[e];
  int slot = slotmap[d];
  int sn = 0; float vv = 0.f;
  if (slot >= 0) { sn = src[e]; vv = ev[e]; }
  unsigned long long m = __ballot(slot >= 0);
  while (m) {
    int j = __ffsll(m) - 1;
    m &= m - 1;
    int sl = __shfl(slot, j);
    int s2 = __shfl(sn, j);
    float v = __shfl(vv, j);
    float2 em = *(const float2*)&emb[(size_t)s2 * 128 + 2 * lane];
    atomicAdd(&agg[sl * 128 + 2 * lane],     em.x * v);
    atomicAdd(&agg[sl * 128 + 2 * lane + 1], em.y * v);
    if (lane == 0) atomicAdd(&cnt[sl], 1.f);
  }
}

// ---------------- divide by count ----------------
__global__ void k_div(float* __restrict__ agg, const float* __restrict__ cnt) {
  int i = blockIdx.x * blockDim.x + threadIdx.x;
  agg[i] /= fmaxf(cnt[i >> 7], 1.f);
}

// ---------------- fuse W_f = w_ih @ W1, bias_f ----------------
__global__ void k_fuse(const float* __restrict__ w_ih, const float* __restrict__ W1,
                       const float* __restrict__ b1, const float* __restrict__ b_ih,
                       const float* __restrict__ b_hh,
                       float* __restrict__ Wf, float* __restrict__ bf) {
  int row = blockIdx.x;
  int e = threadIdx.x;
  float acc = 0.f;
  for (int m2 = 0; m2 < 256; ++m2) acc += w_ih[row * 256 + m2] * W1[m2 * 128 + e];
  Wf[row * 128 + e] = acc;
  if (e == 0) {
    float bacc = b_ih[row] + b_hh[row];
    for (int m2 = 0; m2 < 256; ++m2) bacc += w_ih[row * 256 + m2] * b1[m2];
    bf[row] = bacc;
  }
}

// ---------------- pre-gates GEMM: preg[t][s][m][q][d] ----------------
__global__ __launch_bounds__(256, 2) void k_pregemm(
    const float* __restrict__ hnode, const float* __restrict__ Wf,
    const float* __restrict__ bf, const int* __restrict__ slotmap,
    const int* __restrict__ input_ids, float* __restrict__ preg) {
  __shared__ float Ash[64][132];
  __shared__ float Bsh[64][132];
  __shared__ int slots[64];
  int tid = threadIdx.x;
  int bm = (blockIdx.x & 63) * 64;
  int bn = (blockIdx.x >> 6) * 64;
  if (tid < 64) slots[tid] = slotmap[input_ids[bm + tid]];
  __syncthreads();
#pragma unroll
  for (int i = 0; i < 8; ++i) {
    int idx = tid + 256 * i;
    int r = idx >> 5, c = idx & 31;
    *(float4*)&Ash[r][c * 4] = *(const float4*)&hnode[slots[r] * 128 + c * 4];
    *(float4*)&Bsh[r][c * 4] = *(const float4*)&Wf[(bn + r) * 128 + c * 4];
  }
  __syncthreads();
  int tx = tid & 15, ty = tid >> 4;
  float acc[4][4] = {};
  for (int k = 0; k < 128; k += 4) {
    float4 a[4], bb[4];
#pragma unroll
    for (int i = 0; i < 4; ++i) a[i] = *(const float4*)&Ash[tx + 16 * i][k];
#pragma unroll
    for (int j = 0; j < 4; ++j) bb[j] = *(const float4*)&Bsh[ty + 16 * j][k];
#pragma unroll
    for (int i = 0; i < 4; ++i)
#pragma unroll
      for (int j = 0; j < 4; ++j)
        acc[i][j] += a[i].x * bb[j].x + a[i].y * bb[j].y + a[i].z * bb[j].z + a[i].w * bb[j].w;
  }
#pragma unroll
  for (int j = 0; j < 4; ++j) {
    int row = bn + ty + 16 * j;
    float bias = bf[row];
    int q  = row >> 8;
    int mm = (row >> 5) & 7;
    int dl = row & 31;
#pragma unroll
    for (int i = 0; i < 4; ++i) {
      int p = bm + tx + 16 * i;
      int s = p >> 7, tt = p & 127;
      preg[(((size_t)(tt * 32 + s) * 8 + mm) * 4 + q) * 32 + dl] = acc[i][j] + bias;
    }
  }
}

// ---------------- LSTM: 32 seq-groups x 8 members, L2-atomic exchange ----------------
// Blocks self-organize by PHYSICAL chiplet (HW_REG_XCC_ID + rank atomics) so all 8
// members of a sequence share one XCD/L2. Producer publishes {f32 h, u32 tag} pairs
// with a plain store (write-through L1 -> lands in the shared XCD L2) + an agent-scope
// store to the Y mirror (IF$, correct under any placement). Consumers poll X with
// global_atomic_add_x2(+0, sc0): atomics have no L1 path -- they EXECUTE in the L2 and
// return its current copy, so a same-L2 store is always observed (this is the fix for
// the sc0-load poll, which kept hitting a stale L1 line and never matched). The RMW is
// indivisible at the L2 bank => no tearing vs the 8B store. Y checked every 4th spin
// as the cross-XCD fallback; a tag match on either path yields a valid value.
__global__ __launch_bounds__(256, 1) void k_lstm(
    const float* __restrict__ w_hh, const float* __restrict__ preg,
    float* __restrict__ hs, unsigned long long* __restrict__ ghb,
    int* __restrict__ ctrl) {
  __shared__ float h_lds[512];           // 2 x 256 floats, xor-swizzled
  __shared__ int sh_role;
  int tid = threadIdx.x;

  if (tid == 0) {
    unsigned xcd;
    asm volatile("s_getreg_b32 %0, hwreg(HW_REG_XCC_ID)" : "=s"(xcd));
    xcd &= 7;
    int r = atomicAdd(&ctrl[xcd], 1);          // rank within my physical XCD
    int role;
    if (r < 32) {
      role = (int)xcd * 32 + r;
      atomicAdd(&ctrl[8], 1);                  // arrivals
    } else {
      int o = atomicAdd(&ctrl[9], 1);          // overflow rank
      atomicAdd(&ctrl[8], 1);
      while (__hip_atomic_load(&ctrl[8], __ATOMIC_RELAXED, __HIP_MEMORY_SCOPE_AGENT) < NB) {}
      int acc = 0; role = 0;
      for (int x2 = 0; x2 < 8; ++x2) {
        int c = __hip_atomic_load(&ctrl[x2], __ATOMIC_RELAXED, __HIP_MEMORY_SCOPE_AGENT);
        if (c > 32) c = 32;
        int miss = 32 - c;
        if (o >= acc && o < acc + miss) role = x2 * 32 + c + (o - acc);
        acc += miss;
      }
    }
    sh_role = role;
  }
  __syncthreads();
  const int role = sh_role;
  const int s = 4 * (role >> 5) + ((role >> 3) & 3);  // sequence (XCD-local group)
  const int m = role & 7;                             // member: owns dims 32m..32m+31

  int lane = tid & 63, wave = tid >> 6;
  int x = lane & 7, seg = lane >> 3;     // seg 0..7: k-range [32seg, 32seg+32)
  int combo = x + 8 * wave;              // local dim 0..31
  const int isSeg0 = (seg == 0);

  // weights: rows q*256 + 32m + combo, k-slice [32seg, 32seg+32)
  f32x4 wv[4][8];
#pragma unroll
  for (int q = 0; q < 4; ++q) {
    const float* wp = w_hh + (q * 256 + 32 * m + combo) * 256 + seg * 32;
#pragma unroll
    for (int i = 0; i < 8; ++i) wv[q][i] = *(const f32x4*)(wp + 4 * i);
  }

  unsigned long long* xbase = ghb + s * 512;   // X: [2][256] pairs
  // swizzled scalar LDS index for dim d = tid (matches f32x4 read pattern)
  int fi = tid >> 2, jj = tid & 3;
  int ldsw = (((fi >> 3) * 8) + ((fi & 7) ^ (fi >> 3))) * 4 + jj;

  float c_st = 0.f;                       // cell state (seg0 lanes)
  unsigned long long z64 = 0ULL;          // atomic add operand (returns old value)

  for (int t = 0; t < TSTEPS; ++t) {
    // poll own pair until tag == t; the value in the same 8B is h[t][tid]
    unsigned long long* px = xbase + (t & 1) * 256 + tid;
    unsigned long long pr;
    int gd = 0;
    for (;;) {
      // L2-executed atomic read: add 0, return current pair (sc0 = return old).
      asm volatile("global_atomic_add_x2 %0, %1, %2, off sc0\n\ts_waitcnt vmcnt(0)"
                   : "=v"(pr) : "v"(px), "v"(z64) : "memory");
      if ((unsigned)(pr >> 32) == (unsigned)t) break;
      if ((gd & 3) == 3) {
        pr = __hip_atomic_load(px + YOFFP, __ATOMIC_RELAXED, __HIP_MEMORY_SCOPE_AGENT);
        if ((unsigned)(pr >> 32) == (unsigned)t) break;
      }
      if (++gd >= (1 << 20)) break;
    }
    // prefetch pre-gates AFTER the poll: L2 latency hides under LDS/barrier/dots
    float pg[4] = {0.f, 0.f, 0.f, 0.f};
    if (isSeg0) {
      const float* pb = preg + (((size_t)(t * 32 + s) * 8 + m) * 4) * 32 + combo;
#pragma unroll
      for (int q = 0; q < 4; ++q) pg[q] = pb[q * 32];
    }
    h_lds[(t & 1) * 256 + ldsw] = __uint_as_float((unsigned)pr);
    __syncthreads();
    // partial dots: 4 gate-rows x 32 k per thread
    const f32x4* lds4 = (const f32x4*)(h_lds + (t & 1) * 256);
    float acc[4] = {0.f, 0.f, 0.f, 0.f};
#pragma unroll
    for (int i = 0; i < 8; ++i) {
      f32x4 hv = lds4[seg * 8 + (i ^ seg)];
#pragma unroll
      for (int q = 0; q < 4; ++q)
        acc[q] += wv[q][i].x * hv.x + wv[q][i].y * hv.y
                + wv[q][i].z * hv.z + wv[q][i].w * hv.w;
    }
    // reduce over the 8 k-segments (lane bits 3..5)
#pragma unroll
    for (int q = 0; q < 4; ++q) {
      float v = acc[q];
      v += __shfl_xor(v, 8);
      v += __shfl_xor(v, 16);
      v += __shfl_xor(v, 32);
      acc[q] = v;
    }
    // gate math + tagged publish (seg0 lanes own dim=combo)
    if (isSeg0) {
      float gi = acc[0] + pg[0];
      float gf = acc[1] + pg[1];
      float gg = acc[2] + pg[2];
      float go = acc[3] + pg[3];
      float si = 1.f / (1.f + expf(-gi));
      float sf = 1.f / (1.f + expf(-gf));
      float so = 1.f / (1.f + expf(-go));
      float cc = sf * c_st + si * tanhf(gg);
      float hh = so * tanhf(cc);
      c_st = cc;
      unsigned long long pk =
          ((unsigned long long)(unsigned)(t + 1) << 32) |
          (unsigned long long)__float_as_uint(hh);
      unsigned long long* xp = xbase + ((t + 1) & 1) * 256 + 32 * m + combo;
      // X first (plain store, write-through into the shared XCD L2), then Y (IF$)
      asm volatile("global_store_dwordx2 %0, %1, off sc0"
                   :: "v"(xp), "v"(pk) : "memory");
      __hip_atomic_store(xp + YOFFP, pk, __ATOMIC_RELAXED, __HIP_MEMORY_SCOPE_AGENT);
      hs[(size_t)(t + 1) * 8192 + s * 256 + 32 * m + combo] = hh;  // history
    }
    // no trailing barrier: LDS double-buffer + next-step barrier protect h_lds
  }
}

// ---------------- final: scores, softmax, BCE, argmax ----------------
__global__ void k_final(const float* __restrict__ hs, const int* __restrict__ mask,
                        const float* __restrict__ labels, const float* __restrict__ W2,
                        const float* __restrict__ b2, float* __restrict__ out) {
  __shared__ float scores[32];
  __shared__ float errpart[8];
  int tid = threadIdx.x;
  if (tid < 32) {
    int len = 0;
    for (int t = 0; t < 128; ++t) len += mask[tid * 128 + t];
    if (len < 1) len = 1;
    const float* hl = hs + (size_t)len * 8192 + tid * 256;
    float acc = b2[0];
    for (int k = 0; k < 256; ++k) acc += hl[k] * W2[k];
    scores[tid] = acc;
  }
  __syncthreads();
  if (tid < 8) {
    float sc[4];
#pragma unroll
    for (int i = 0; i < 4; ++i) sc[i] = scores[tid * 4 + i];
    float mx = fmaxf(fmaxf(sc[0], sc[1]), fmaxf(sc[2], sc[3]));
    float ex[4], ssum = 0.f;
#pragma unroll
    for (int i = 0; i < 4; ++i) { ex[i] = expf(sc[i] - mx); ssum += ex[i]; }
    float esum = 0.f; int am = 0; float best = -1e30f;
#pragma unroll
    for (int i = 0; i < 4; ++i) {
      float p = ex[i] / ssum;
      float li = labels[tid * 4 + i];
      esum += fmaxf(p, 0.f) - p * li + log1pf(expf(-fabsf(p)));
      if (p > best) { best = p; am = i; }
    }
    errpart[tid] = esum;
    out[1 + tid] = (float)am;
  }
  __syncthreads();
  if (tid == 0) {
    float e = 0.f;
    for (int i = 0; i < 8; ++i) e += errpart[i];
    out[0] = e / 32.f;
  }
}

extern "C" void kernel_launch(void* const* d_in, const int* in_sizes, int n_in,
                              void* d_out, int out_size, void* d_ws, size_t ws_size,
                              hipStream_t stream) {
  const int*   input_ids  = (const int*)d_in[0];
  const int*   input_mask = (const int*)d_in[1];
  const float* labels     = (const float*)d_in[2];
  const int*   src        = (const int*)d_in[3];
  const int*   dst        = (const int*)d_in[4];
  const float* ev         = (const float*)d_in[5];
  const float* node_emb   = (const float*)d_in[6];
  const float* W1         = (const float*)d_in[7];
  const float* b1         = (const float*)d_in[8];
  const float* w_ih       = (const float*)d_in[9];
  const float* w_hh       = (const float*)d_in[10];
  const float* b_ih       = (const float*)d_in[11];
  const float* b_hh       = (const float*)d_in[12];
  const float* W2         = (const float*)d_in[13];
  const float* b2         = (const float*)d_in[14];
  float* out = (float*)d_out;
  char* ws = (char*)d_ws;
  int*   slotmap = (int*)(ws + OFF_SLOT);
  float* agg     = (float*)(ws + OFF_AGG);
  float* cnt     = (float*)(ws + OFF_CNT);
  float* Wf      = (float*)(ws + OFF_WF);
  float* biasf   = (float*)(ws + OFF_BIASF);
  float* preg    = (float*)(ws + OFF_PREG);
  float* hs      = (float*)(ws + OFF_HS);
  unsigned long long* ghb = (unsigned long long*)(ws + OFF_GHB);
  int*   ctrl    = (int*)(ws + OFF_CTRL);

  hipLaunchKernelGGL(k_init,    dim3(2048), dim3(256), 0, stream, slotmap, agg, cnt, hs);
  hipLaunchKernelGGL(k_mark,    dim3(16),   dim3(256), 0, stream, input_ids, slotmap);
  hipLaunchKernelGGL(k_edge,    dim3(6250), dim3(256), 0, stream, src, dst, ev, node_emb, slotmap, agg, cnt);
  hipLaunchKernelGGL(k_div,     dim3(2048), dim3(256), 0, stream, agg, cnt);
  hipLaunchKernelGGL(k_fuse,    dim3(1024), dim3(128), 0, stream, w_ih, W1, b1, b_ih, b_hh, Wf, biasf);
  hipLaunchKernelGGL(k_pregemm, dim3(1024), dim3(256), 0, stream, agg, Wf, biasf, slotmap, input_ids, preg);
  hipLaunchKernelGGL(k_init2,   dim3(64),   dim3(256), 0, stream, ghb, ctrl);
  hipLaunchKernelGGL(k_lstm,    dim3(NB),   dim3(256), 0, stream, w_hh, preg, hs, ghb, ctrl);
  hipLaunchKernelGGL(k_final,   dim3(1),    dim3(64),  0, stream, hs, input_mask, labels, W2, b2, out);
}